// Round 1
// 1452.224 us; speedup vs baseline: 1.3895x; 1.3895x over previous
//
#include <hip/hip_runtime.h>
#include <math.h>

#define B_ 2
#define T_ 2048
#define D_ 1024
#define H_ 16
#define DH_ 64
#define TD3_ 3072
#define NROWS_ 4096            // B*T
#define BHT_ 65536             // B*H*T

typedef __attribute__((ext_vector_type(4))) float floatx4;
typedef __attribute__((ext_vector_type(8))) short short8;

__device__ __forceinline__ unsigned short f2bf(float x) {
    union { float f; unsigned u; } c; c.f = x;
    unsigned r = c.u + 0x7FFF + ((c.u >> 16) & 1);
    return (unsigned short)(r >> 16);
}

// async global->LDS, 16B per lane; LDS dest = wave-uniform base + lane*16
__device__ __forceinline__ void gload_lds16(const void* g, void* lds) {
    __builtin_amdgcn_global_load_lds(
        (const __attribute__((address_space(1))) unsigned int*)(unsigned long long)(uintptr_t)g,
        (__attribute__((address_space(3))) unsigned int*)(unsigned int)(uintptr_t)lds,
        16, 0, 0);
}

// ---------------- reduction helpers ----------------
__device__ __forceinline__ float wave_sum(float v) {
#pragma unroll
    for (int o = 32; o > 0; o >>= 1) v += __shfl_down(v, o, 64);
    return v;
}
__device__ __forceinline__ float wave_max(float v) {
#pragma unroll
    for (int o = 32; o > 0; o >>= 1) v = fmaxf(v, __shfl_down(v, o, 64));
    return v;
}
__device__ __forceinline__ float block_sum(float v, float* red) {
    v = wave_sum(v);
    __syncthreads();
    if ((threadIdx.x & 63) == 0) red[threadIdx.x >> 6] = v;
    __syncthreads();
    return red[0] + red[1] + red[2] + red[3];
}
__device__ __forceinline__ float block_max(float v, float* red) {
    v = wave_max(v);
    __syncthreads();
    if ((threadIdx.x & 63) == 0) red[threadIdx.x >> 6] = v;
    __syncthreads();
    return fmaxf(fmaxf(red[0], red[1]), fmaxf(red[2], red[3]));
}

// ---------------- LayerNorm -> bf16 out ----------------
__global__ __launch_bounds__(256)
void ln_bf16_kernel(const float* __restrict__ x, const float* __restrict__ g,
                    const float* __restrict__ bb, unsigned short* __restrict__ out)
{
    __shared__ float red[4];
    const int row = blockIdx.x;
    const float* xr = x + (size_t)row * D_;
    unsigned short* orow = out + (size_t)row * D_;
    const int i = threadIdx.x * 4;
    float4 v = *(const float4*)(xr + i);
    float s = v.x + v.y + v.z + v.w;
    float ss = v.x * v.x + v.y * v.y + v.z * v.z + v.w * v.w;
    const float ms = block_sum(s, red);
    const float mss = block_sum(ss, red);
    const float mu = ms * (1.0f / D_);
    const float var = mss * (1.0f / D_) - mu * mu;
    const float inv = rsqrtf(var + 1e-5f);
    float4 gv = *(const float4*)(g + i);
    float4 bv = *(const float4*)(bb + i);
    ushort4 o;
    o.x = f2bf((v.x - mu) * inv * gv.x + bv.x);
    o.y = f2bf((v.y - mu) * inv * gv.y + bv.y);
    o.z = f2bf((v.z - mu) * inv * gv.z + bv.z);
    o.w = f2bf((v.w - mu) * inv * gv.w + bv.w);
    *(ushort4*)(orow + i) = o;
}

// ---------------- weight transpose + fp32->bf16: W[K][N] -> Wt[N][K] ----------------
__global__ __launch_bounds__(256)
void transpose_bf16_kernel(const float* __restrict__ W, unsigned short* __restrict__ Wt,
                           int K, int N)
{
    __shared__ unsigned short tile[32][33];
    const int n0 = blockIdx.x * 32, k0 = blockIdx.y * 32;
    const int tx = threadIdx.x & 31, ty = threadIdx.x >> 5;   // 32 x 8
#pragma unroll
    for (int r = 0; r < 32; r += 8)
        tile[tx][ty + r] = f2bf(W[(size_t)(k0 + ty + r) * N + n0 + tx]);
    __syncthreads();
#pragma unroll
    for (int r = 0; r < 32; r += 8)
        Wt[(size_t)(n0 + ty + r) * K + k0 + tx] = tile[ty + r][tx];
}

// ---------------- V transpose from bf16 qkv: vT[b][d][t] ----------------
__global__ __launch_bounds__(256)
void vT_kernel(const unsigned short* __restrict__ qkvb, unsigned short* __restrict__ vT)
{
    __shared__ unsigned short tile[32][33];
    const int t0 = blockIdx.x * 32;     // time tile
    const int d0 = blockIdx.y * 32;     // hd tile (h*64+dh flattened = 0..1023)
    const int b = blockIdx.z;
    const int tx = threadIdx.x & 31, ty = threadIdx.x >> 5;   // 32 x 8
#pragma unroll
    for (int r = 0; r < 32; r += 8)
        tile[ty + r][tx] = qkvb[(size_t)(b * T_ + t0 + ty + r) * TD3_ + 2 * D_ + d0 + tx];
    __syncthreads();
#pragma unroll
    for (int r = 0; r < 32; r += 8)
        vT[(size_t)(b * D_ + d0 + ty + r) * T_ + t0 + tx] = tile[tx][ty + r];
}

// ---------------- bf16 MFMA GEMM (m97 structure): C = A[M][K] @ Bt[N][K]^T ----------------
template<int OUT_BF16, int DO_GELU, int HAS_BIAS, int HAS_RESID>
__global__ __launch_bounds__(256)
void gemm_bt_kernel(const unsigned short* __restrict__ A,
                    const unsigned short* __restrict__ Bt,
                    const float* __restrict__ bias,
                    const float* __restrict__ resid,
                    void* __restrict__ Cv,
                    int M, int N, int K)
{
    __shared__ __align__(16) unsigned short As[128 * 32];   // [m][k] 8KB
    __shared__ __align__(16) unsigned short Bs[128 * 32];   // [n][k] 8KB
    const int tid = threadIdx.x;
    const int wave = tid >> 6;
    const int lane = tid & 63;
    const int m0 = blockIdx.x * 128;
    const int n0 = blockIdx.y * 128;
    const int wm = (wave & 1) * 64;
    const int wn = (wave >> 1) * 64;

    floatx4 acc[4][4];
#pragma unroll
    for (int i = 0; i < 4; ++i)
#pragma unroll
        for (int j = 0; j < 4; ++j) acc[i][j] = (floatx4){0.f, 0.f, 0.f, 0.f};

    // staging: wave w covers tile rows [32w, 32w+32) via 2 issues of 16 rows
    const int srow = lane >> 2;             // 0..15
    const int skoff = (lane & 3) * 8;       // bf16 elems within the 32-wide k-slab
    const unsigned short* Ag = A + (size_t)(m0 + 32 * wave + srow) * K + skoff;
    const unsigned short* Bg = Bt + (size_t)(n0 + 32 * wave + srow) * K + skoff;
    unsigned short* AsW = As + 1024 * wave;
    unsigned short* BsW = Bs + 1024 * wave;

    const int frow = lane & 15;
    const int fk = (lane >> 4) * 8;

    for (int k0 = 0; k0 < K; k0 += 32) {
        gload_lds16(Ag + k0, AsW);
        gload_lds16(Ag + (size_t)16 * K + k0, AsW + 512);
        gload_lds16(Bg + k0, BsW);
        gload_lds16(Bg + (size_t)16 * K + k0, BsW + 512);
        __syncthreads();
        short8 af[4], bfv[4];
#pragma unroll
        for (int mi = 0; mi < 4; ++mi)
            af[mi] = *(const short8*)&As[(wm + mi * 16 + frow) * 32 + fk];
#pragma unroll
        for (int ni = 0; ni < 4; ++ni)
            bfv[ni] = *(const short8*)&Bs[(wn + ni * 16 + frow) * 32 + fk];
#pragma unroll
        for (int mi = 0; mi < 4; ++mi)
#pragma unroll
            for (int ni = 0; ni < 4; ++ni)
                acc[mi][ni] = __builtin_amdgcn_mfma_f32_16x16x32_bf16(
                    af[mi], bfv[ni], acc[mi][ni], 0, 0, 0);
        __syncthreads();
    }

    // epilogue: C/D layout col=lane&15, row=(lane>>4)*4+reg
#pragma unroll
    for (int ni = 0; ni < 4; ++ni) {
        const int col = n0 + wn + ni * 16 + (lane & 15);
        const float bv = HAS_BIAS ? bias[col] : 0.f;
#pragma unroll
        for (int mi = 0; mi < 4; ++mi) {
#pragma unroll
            for (int r = 0; r < 4; ++r) {
                const int row = m0 + wm + mi * 16 + (lane >> 4) * 4 + r;
                float v = acc[mi][ni][r] + bv;
                if (DO_GELU) v = 0.5f * v * (1.0f + erff(v * 0.70710678118654752f));
                if (HAS_RESID) v += resid[(size_t)row * N + col];
                if (OUT_BF16) ((unsigned short*)Cv)[(size_t)row * N + col] = f2bf(v);
                else          ((float*)Cv)[(size_t)row * N + col] = v;
            }
        }
    }
}

// ---------------- logits via MFMA: s = QK^T/8 - dists, 64x64 tiles (fp32 out) ----------------
__global__ __launch_bounds__(256)
void logits_mfma_kernel(const unsigned short* __restrict__ qkvb,
                        const float* __restrict__ dists,
                        float* __restrict__ wout)
{
    const int it = blockIdx.x, jt = blockIdx.y;
    if (jt > it) return;
    const int bh = blockIdx.z;
    const int b = bh >> 4, hh = bh & 15;
    const int i0 = it << 6, j0 = jt << 6;
    __shared__ __align__(16) unsigned short Qs[64 * 64];   // swizzled [i][d] 8KB
    __shared__ __align__(16) unsigned short Ks[64 * 64];   // swizzled [j][d] 8KB
    const int tid = threadIdx.x;
    const int wave = tid >> 6, lane = tid & 63;

    // stage q/k tiles (bf16 copy with XOR-16B swizzle): row = tid>>2, col groups g0, g0+1
    {
        const int r = tid >> 2;
        const int g0 = (tid & 3) * 2;        // 16B-group index (0..7)
        const int sw = r & 7;
        const unsigned short* qp = qkvb + (size_t)(b * T_ + i0 + r) * TD3_ + hh * DH_ + g0 * 8;
        const unsigned short* kp = qkvb + (size_t)(b * T_ + j0 + r) * TD3_ + D_ + hh * DH_ + g0 * 8;
        short8 q0 = *(const short8*)qp;
        short8 q1 = *(const short8*)(qp + 8);
        short8 k0v = *(const short8*)kp;
        short8 k1v = *(const short8*)(kp + 8);
        *(short8*)&Qs[r * 64 + ((g0 ^ sw) * 8)]       = q0;
        *(short8*)&Qs[r * 64 + (((g0 + 1) ^ sw) * 8)] = q1;
        *(short8*)&Ks[r * 64 + ((g0 ^ sw) * 8)]       = k0v;
        *(short8*)&Ks[r * 64 + (((g0 + 1) ^ sw) * 8)] = k1v;
    }
    __syncthreads();

    const int wm = (wave & 1) * 32, wn = (wave >> 1) * 32;
    const int frow = lane & 15;
    floatx4 acc[2][2];
#pragma unroll
    for (int i = 0; i < 2; ++i)
#pragma unroll
        for (int j = 0; j < 2; ++j) acc[i][j] = (floatx4){0.f, 0.f, 0.f, 0.f};

#pragma unroll
    for (int kk = 0; kk < 2; ++kk) {
        const int g = kk * 4 + (lane >> 4);   // 16B-group of this lane's k-slab
        short8 aq[2], bk[2];
#pragma unroll
        for (int mi = 0; mi < 2; ++mi) {
            const int r = wm + mi * 16 + frow;
            aq[mi] = *(const short8*)&Qs[r * 64 + ((g ^ (r & 7)) * 8)];
        }
#pragma unroll
        for (int ni = 0; ni < 2; ++ni) {
            const int r = wn + ni * 16 + frow;
            bk[ni] = *(const short8*)&Ks[r * 64 + ((g ^ (r & 7)) * 8)];
        }
#pragma unroll
        for (int mi = 0; mi < 2; ++mi)
#pragma unroll
            for (int ni = 0; ni < 2; ++ni)
                acc[mi][ni] = __builtin_amdgcn_mfma_f32_16x16x32_bf16(
                    aq[mi], bk[ni], acc[mi][ni], 0, 0, 0);
    }

    float* wbase = wout + (size_t)bh * T_ * T_;
    const float* dbase = dists + (size_t)b * T_ * T_;
#pragma unroll
    for (int ni = 0; ni < 2; ++ni) {
        const int gj = j0 + wn + ni * 16 + (lane & 15);
#pragma unroll
        for (int mi = 0; mi < 2; ++mi) {
#pragma unroll
            for (int r = 0; r < 4; ++r) {
                const int gi = i0 + wm + mi * 16 + (lane >> 4) * 4 + r;
                if (gj <= gi)
                    wbase[(size_t)gi * T_ + gj] = acc[mi][ni][r] * 0.125f
                                                - dbase[(size_t)gi * T_ + gj];
            }
        }
    }
}

// ---------------- row softmax (in place on w), zero-fill causal, energy partials ----------------
__global__ __launch_bounds__(256)
void softmax_kernel(float* __restrict__ w, const float* __restrict__ dists,
                    float* __restrict__ parts)
{
    __shared__ float buf[T_];
    __shared__ float red[4];
    const int row = blockIdx.x;             // bh*T + i
    const int i = row & (T_ - 1);
    const int bh = row >> 11;
    const int b = bh >> 4;
    float* wr = w + (size_t)row * T_;
    const float* dr = dists + ((size_t)(b * T_ + i)) * T_;
    const int n = i + 1;
    float lmax = -3.4e38f;
    for (int j = threadIdx.x; j < n; j += 256) {
        float v = wr[j];
        buf[j] = v;
        lmax = fmaxf(lmax, v);
    }
    const float mx = block_max(lmax, red);
    float lsum = 0.f;
    for (int j = threadIdx.x; j < n; j += 256) {
        float e = expf(buf[j] - mx);
        buf[j] = e;
        lsum += e;
    }
    const float S = block_sum(lsum, red);
    const float inv = 1.0f / S;
    float de = 0.f, fe = 0.f;
    for (int j = threadIdx.x; j < n; j += 256) {
        float ww = buf[j] * inv;
        wr[j] = ww;
        de += ww * dr[j];
        fe -= ww * logf(ww + 1e-9f);
    }
    for (int j = n + (int)threadIdx.x; j < T_; j += 256) wr[j] = 0.f;
    de = block_sum(de, red);
    fe = block_sum(fe, red);
    if (threadIdx.x == 0) {
        parts[row] = de;
        parts[BHT_ + row] = fe;
    }
}

// ---------------- attn = w @ v via MFMA: 64 rows x 64 cols per block ----------------
__global__ __launch_bounds__(256)
void attnv_mfma_kernel(const float* __restrict__ w, const unsigned short* __restrict__ vT,
                       unsigned short* __restrict__ attn)
{
    __shared__ __align__(16) unsigned short Ws[64 * 32];   // [i][j] bf16 4KB
    __shared__ __align__(16) unsigned short Vs[64 * 32];   // [d][j] bf16 4KB
    const int it = blockIdx.x;
    const int bh = blockIdx.y;
    const int b = bh >> 4, hh = bh & 15;
    const int tid = threadIdx.x;
    const int wave = tid >> 6, lane = tid & 63;
    const int wm = (wave & 1) * 32;    // i sub-tile
    const int wn = (wave >> 1) * 32;   // d sub-tile

    floatx4 acc[2][2];
#pragma unroll
    for (int i = 0; i < 2; ++i)
#pragma unroll
        for (int j = 0; j < 2; ++j) acc[i][j] = (floatx4){0.f, 0.f, 0.f, 0.f};

    const float* wbase = w + ((size_t)bh * T_ + (size_t)it * 64) * T_;
    // V staging via global_load_lds: wave covers d-rows [16*wave, 16*wave+16)
    const unsigned short* Vg = vT + ((size_t)(b * D_ + hh * DH_ + 16 * wave + (lane >> 2))) * T_
                             + (lane & 3) * 8;
    unsigned short* VsW = Vs + 512 * wave;
    // W staging (fp32 -> bf16 in regs): thread t: row = t>>2, cols (t&3)*8 .. +8
    const int sr = tid >> 2, sc = (tid & 3) * 8;
    const float* Wg = wbase + (size_t)sr * T_ + sc;

    const int frow = lane & 15;
    const int fk = (lane >> 4) * 8;
    const int jend = (it + 1) * 64;     // upper triangle of w is zero-filled by softmax

    for (int j0 = 0; j0 < jend; j0 += 32) {
        gload_lds16(Vg + j0, VsW);
        float4 a0 = *(const float4*)(Wg + j0);
        float4 a1 = *(const float4*)(Wg + j0 + 4);
        union { short8 s; unsigned short u[8]; } pk;
        pk.u[0] = f2bf(a0.x); pk.u[1] = f2bf(a0.y); pk.u[2] = f2bf(a0.z); pk.u[3] = f2bf(a0.w);
        pk.u[4] = f2bf(a1.x); pk.u[5] = f2bf(a1.y); pk.u[6] = f2bf(a1.z); pk.u[7] = f2bf(a1.w);
        *(short8*)&Ws[sr * 32 + sc] = pk.s;
        __syncthreads();
        short8 af[2], bv[2];
#pragma unroll
        for (int mi = 0; mi < 2; ++mi)
            af[mi] = *(const short8*)&Ws[(wm + mi * 16 + frow) * 32 + fk];
#pragma unroll
        for (int ni = 0; ni < 2; ++ni)
            bv[ni] = *(const short8*)&Vs[(wn + ni * 16 + frow) * 32 + fk];
#pragma unroll
        for (int mi = 0; mi < 2; ++mi)
#pragma unroll
            for (int ni = 0; ni < 2; ++ni)
                acc[mi][ni] = __builtin_amdgcn_mfma_f32_16x16x32_bf16(
                    af[mi], bv[ni], acc[mi][ni], 0, 0, 0);
        __syncthreads();
    }

#pragma unroll
    for (int ni = 0; ni < 2; ++ni) {
        const int d = wn + ni * 16 + (lane & 15);
#pragma unroll
        for (int mi = 0; mi < 2; ++mi) {
#pragma unroll
            for (int r = 0; r < 4; ++r) {
                const int gi = it * 64 + wm + mi * 16 + (lane >> 4) * 4 + r;
                attn[((size_t)(b * T_ + gi)) * D_ + hh * DH_ + d] = f2bf(acc[mi][ni][r]);
            }
        }
    }
}

// ---------------- stage-2 energy reduction ----------------
__global__ __launch_bounds__(256)
void reduce_energy_kernel(const float* __restrict__ parts, float* __restrict__ out_e)
{
    __shared__ float red[4];
    const float* p = parts + (size_t)blockIdx.y * BHT_ + (size_t)blockIdx.x * 1024;
    float s = 0.f;
    for (int i = threadIdx.x; i < 1024; i += 256) s += p[i];
    s = block_sum(s, red);
    if (threadIdx.x == 0) atomicAdd(&out_e[blockIdx.y], s * (1.0f / BHT_));
}

// ---------------- launch ----------------
extern "C" void kernel_launch(void* const* d_in, const int* in_sizes, int n_in,
                              void* d_out_v, int out_size, void* d_ws, size_t ws_size,
                              hipStream_t stream)
{
    const float* x    = (const float*)d_in[0];
    const float* td   = (const float*)d_in[1];
    const float* ln1g = (const float*)d_in[2];
    const float* ln1b = (const float*)d_in[3];
    const float* wqkv = (const float*)d_in[4];
    const float* wproj= (const float*)d_in[5];
    const float* ln2g = (const float*)d_in[6];
    const float* ln2b = (const float*)d_in[7];
    const float* w1   = (const float*)d_in[8];
    const float* b1   = (const float*)d_in[9];
    const float* w2   = (const float*)d_in[10];
    const float* b2   = (const float*)d_in[11];
    float* out = (float*)d_out_v;

    // output layout: x (4194304) | dist_e (1) | flop_e (1) | w (134217728) | token_dists (8388608)
    float* out_x  = out;
    float* out_e  = out + 4194304;
    float* out_w  = out + 4194306;
    float* out_td = out + 138412034;

    char* p = (char*)d_ws;
    unsigned short* qkvb = (unsigned short*)p; p += (size_t)NROWS_ * TD3_ * 2;       // bf16 qkv, 24MB
    float* x1    = (float*)p;              p += (size_t)NROWS_ * D_ * 4;             // 16MB
    float* parts = (float*)p;              p += (size_t)2 * BHT_ * 4;                // 0.5MB
    unsigned short* hb    = (unsigned short*)p; p += (size_t)NROWS_ * D_ * 2;        // 8MB
    unsigned short* attnb = (unsigned short*)p; p += (size_t)NROWS_ * D_ * 2;        // 8MB
    unsigned short* h2b   = (unsigned short*)p; p += (size_t)NROWS_ * D_ * 2;        // 8MB
    unsigned short* ffn1b = (unsigned short*)p; p += (size_t)NROWS_ * 4 * D_ * 2;    // 32MB
    unsigned short* wqkvT = (unsigned short*)p; p += (size_t)TD3_ * D_ * 2;          // 6MB
    unsigned short* wprojT= (unsigned short*)p; p += (size_t)D_ * D_ * 2;            // 2MB
    unsigned short* w1T   = (unsigned short*)p; p += (size_t)4 * D_ * D_ * 2;        // 8MB
    unsigned short* w2T   = (unsigned short*)p; p += (size_t)4 * D_ * D_ * 2;        // 8MB
    unsigned short* vTb   = (unsigned short*)p; p += (size_t)B_ * D_ * T_ * 2;       // 8MB

    hipMemsetAsync(out_e, 0, 2 * sizeof(float), stream);

    // weight transposes (fp32 [K][N] -> bf16 [N][K])
    transpose_bf16_kernel<<<dim3(TD3_ / 32, D_ / 32), 256, 0, stream>>>(wqkv, wqkvT, D_, TD3_);
    transpose_bf16_kernel<<<dim3(D_ / 32, D_ / 32), 256, 0, stream>>>(wproj, wprojT, D_, D_);
    transpose_bf16_kernel<<<dim3(4 * D_ / 32, D_ / 32), 256, 0, stream>>>(w1, w1T, D_, 4 * D_);
    transpose_bf16_kernel<<<dim3(D_ / 32, 4 * D_ / 32), 256, 0, stream>>>(w2, w2T, 4 * D_, D_);

    ln_bf16_kernel<<<NROWS_, 256, 0, stream>>>(x, ln1g, ln1b, hb);

    // QKV GEMM -> bf16 output
    gemm_bt_kernel<1, 0, 0, 0><<<dim3(NROWS_ / 128, TD3_ / 128), 256, 0, stream>>>(
        hb, wqkvT, nullptr, nullptr, qkvb, NROWS_, TD3_, D_);

    // V^T extraction (bf16 [b][d][t])
    vT_kernel<<<dim3(T_ / 32, D_ / 32, B_), 256, 0, stream>>>(qkvb, vTb);

    dim3 gl(T_ / 64, T_ / 64, B_ * H_);
    logits_mfma_kernel<<<gl, 256, 0, stream>>>(qkvb, td, out_w);

    softmax_kernel<<<BHT_, 256, 0, stream>>>(out_w, td, parts);

    dim3 ga(T_ / 64, B_ * H_);
    attnv_mfma_kernel<<<ga, 256, 0, stream>>>(out_w, vTb, attnb);

    gemm_bt_kernel<0, 0, 0, 1><<<dim3(NROWS_ / 128, D_ / 128), 256, 0, stream>>>(
        attnb, wprojT, nullptr, x, x1, NROWS_, D_, D_);

    ln_bf16_kernel<<<NROWS_, 256, 0, stream>>>(x1, ln2g, ln2b, h2b);

    gemm_bt_kernel<1, 1, 1, 0><<<dim3(NROWS_ / 128, 4 * D_ / 128), 256, 0, stream>>>(
        h2b, w1T, b1, nullptr, ffn1b, NROWS_, 4 * D_, D_);

    gemm_bt_kernel<0, 0, 1, 1><<<dim3(NROWS_ / 128, D_ / 128), 256, 0, stream>>>(
        ffn1b, w2T, b2, x1, out_x, NROWS_, D_, 4 * D_);

    reduce_energy_kernel<<<dim3(64, 2), 256, 0, stream>>>(parts, out_e);

    hipMemcpyAsync(out_td, td, (size_t)B_ * T_ * T_ * sizeof(float),
                   hipMemcpyDeviceToDevice, stream);
}

// Round 2
// 1220.638 us; speedup vs baseline: 1.6532x; 1.1897x over previous
//
#include <hip/hip_runtime.h>
#include <math.h>

#define B_ 2
#define T_ 2048
#define D_ 1024
#define H_ 16
#define DH_ 64
#define TD3_ 3072
#define NROWS_ 4096            // B*T
#define BHT_ 65536             // B*H*T

typedef __attribute__((ext_vector_type(4))) float floatx4;
typedef __attribute__((ext_vector_type(8))) short short8;

__device__ __forceinline__ unsigned short f2bf(float x) {
    union { float f; unsigned u; } c; c.f = x;
    unsigned r = c.u + 0x7FFF + ((c.u >> 16) & 1);
    return (unsigned short)(r >> 16);
}

// async global->LDS, 16B per lane; LDS dest = wave-uniform base + lane*16
__device__ __forceinline__ void gload_lds16(const void* g, void* lds) {
    __builtin_amdgcn_global_load_lds(
        (const __attribute__((address_space(1))) unsigned int*)(unsigned long long)(uintptr_t)g,
        (__attribute__((address_space(3))) unsigned int*)(unsigned int)(uintptr_t)lds,
        16, 0, 0);
}

// ---------------- reduction helpers ----------------
__device__ __forceinline__ float wave_sum(float v) {
#pragma unroll
    for (int o = 32; o > 0; o >>= 1) v += __shfl_down(v, o, 64);
    return v;
}
__device__ __forceinline__ float block_sum(float v, float* red) {
    v = wave_sum(v);
    __syncthreads();
    if ((threadIdx.x & 63) == 0) red[threadIdx.x >> 6] = v;
    __syncthreads();
    return red[0] + red[1] + red[2] + red[3];
}

// ---------------- LayerNorm -> bf16 out ----------------
__global__ __launch_bounds__(256)
void ln_bf16_kernel(const float* __restrict__ x, const float* __restrict__ g,
                    const float* __restrict__ bb, unsigned short* __restrict__ out)
{
    __shared__ float red[4];
    const int row = blockIdx.x;
    const float* xr = x + (size_t)row * D_;
    unsigned short* orow = out + (size_t)row * D_;
    const int i = threadIdx.x * 4;
    float4 v = *(const float4*)(xr + i);
    float s = v.x + v.y + v.z + v.w;
    float ss = v.x * v.x + v.y * v.y + v.z * v.z + v.w * v.w;
    const float ms = block_sum(s, red);
    const float mss = block_sum(ss, red);
    const float mu = ms * (1.0f / D_);
    const float var = mss * (1.0f / D_) - mu * mu;
    const float inv = rsqrtf(var + 1e-5f);
    float4 gv = *(const float4*)(g + i);
    float4 bv = *(const float4*)(bb + i);
    ushort4 o;
    o.x = f2bf((v.x - mu) * inv * gv.x + bv.x);
    o.y = f2bf((v.y - mu) * inv * gv.y + bv.y);
    o.z = f2bf((v.z - mu) * inv * gv.z + bv.z);
    o.w = f2bf((v.w - mu) * inv * gv.w + bv.w);
    *(ushort4*)(orow + i) = o;
}

// ---------------- weight transpose + fp32->bf16: W[K][N] -> Wt[N][K] ----------------
__global__ __launch_bounds__(256)
void transpose_bf16_kernel(const float* __restrict__ W, unsigned short* __restrict__ Wt,
                           int K, int N)
{
    __shared__ unsigned short tile[32][33];
    const int n0 = blockIdx.x * 32, k0 = blockIdx.y * 32;
    const int tx = threadIdx.x & 31, ty = threadIdx.x >> 5;   // 32 x 8
#pragma unroll
    for (int r = 0; r < 32; r += 8)
        tile[tx][ty + r] = f2bf(W[(size_t)(k0 + ty + r) * N + n0 + tx]);
    __syncthreads();
#pragma unroll
    for (int r = 0; r < 32; r += 8)
        Wt[(size_t)(n0 + ty + r) * K + k0 + tx] = tile[ty + r][tx];
}

// ---------------- V transpose from bf16 qkv: vT[b][d][t] ----------------
__global__ __launch_bounds__(256)
void vT_kernel(const unsigned short* __restrict__ qkvb, unsigned short* __restrict__ vT)
{
    __shared__ unsigned short tile[32][33];
    const int t0 = blockIdx.x * 32;     // time tile
    const int d0 = blockIdx.y * 32;     // hd tile
    const int b = blockIdx.z;
    const int tx = threadIdx.x & 31, ty = threadIdx.x >> 5;   // 32 x 8
#pragma unroll
    for (int r = 0; r < 32; r += 8)
        tile[ty + r][tx] = qkvb[(size_t)(b * T_ + t0 + ty + r) * TD3_ + 2 * D_ + d0 + tx];
    __syncthreads();
#pragma unroll
    for (int r = 0; r < 32; r += 8)
        vT[(size_t)(b * D_ + d0 + ty + r) * T_ + t0 + tx] = tile[tx][ty + r];
}

// ---------------- bf16 MFMA GEMM (m97 structure): C = A[M][K] @ Bt[N][K]^T ----------------
template<int OUT_BF16, int DO_GELU, int HAS_BIAS, int HAS_RESID>
__global__ __launch_bounds__(256)
void gemm_bt_kernel(const unsigned short* __restrict__ A,
                    const unsigned short* __restrict__ Bt,
                    const float* __restrict__ bias,
                    const float* __restrict__ resid,
                    void* __restrict__ Cv,
                    int M, int N, int K)
{
    __shared__ __align__(16) unsigned short As[128 * 32];   // [m][k] 8KB
    __shared__ __align__(16) unsigned short Bs[128 * 32];   // [n][k] 8KB
    const int tid = threadIdx.x;
    const int wave = tid >> 6;
    const int lane = tid & 63;
    const int m0 = blockIdx.x * 128;
    const int n0 = blockIdx.y * 128;
    const int wm = (wave & 1) * 64;
    const int wn = (wave >> 1) * 64;

    floatx4 acc[4][4];
#pragma unroll
    for (int i = 0; i < 4; ++i)
#pragma unroll
        for (int j = 0; j < 4; ++j) acc[i][j] = (floatx4){0.f, 0.f, 0.f, 0.f};

    const int srow = lane >> 2;             // 0..15
    const int skoff = (lane & 3) * 8;       // bf16 elems within the 32-wide k-slab
    const unsigned short* Ag = A + (size_t)(m0 + 32 * wave + srow) * K + skoff;
    const unsigned short* Bg = Bt + (size_t)(n0 + 32 * wave + srow) * K + skoff;
    unsigned short* AsW = As + 1024 * wave;
    unsigned short* BsW = Bs + 1024 * wave;

    const int frow = lane & 15;
    const int fk = (lane >> 4) * 8;

    for (int k0 = 0; k0 < K; k0 += 32) {
        gload_lds16(Ag + k0, AsW);
        gload_lds16(Ag + (size_t)16 * K + k0, AsW + 512);
        gload_lds16(Bg + k0, BsW);
        gload_lds16(Bg + (size_t)16 * K + k0, BsW + 512);
        __syncthreads();
        short8 af[4], bfv[4];
#pragma unroll
        for (int mi = 0; mi < 4; ++mi)
            af[mi] = *(const short8*)&As[(wm + mi * 16 + frow) * 32 + fk];
#pragma unroll
        for (int ni = 0; ni < 4; ++ni)
            bfv[ni] = *(const short8*)&Bs[(wn + ni * 16 + frow) * 32 + fk];
#pragma unroll
        for (int mi = 0; mi < 4; ++mi)
#pragma unroll
            for (int ni = 0; ni < 4; ++ni)
                acc[mi][ni] = __builtin_amdgcn_mfma_f32_16x16x32_bf16(
                    af[mi], bfv[ni], acc[mi][ni], 0, 0, 0);
        __syncthreads();
    }

#pragma unroll
    for (int ni = 0; ni < 4; ++ni) {
        const int col = n0 + wn + ni * 16 + (lane & 15);
        const float bv = HAS_BIAS ? bias[col] : 0.f;
#pragma unroll
        for (int mi = 0; mi < 4; ++mi) {
#pragma unroll
            for (int r = 0; r < 4; ++r) {
                const int row = m0 + wm + mi * 16 + (lane >> 4) * 4 + r;
                float v = acc[mi][ni][r] + bv;
                if (DO_GELU) v = 0.5f * v * (1.0f + erff(v * 0.70710678118654752f));
                if (HAS_RESID) v += resid[(size_t)row * N + col];
                if (OUT_BF16) ((unsigned short*)Cv)[(size_t)row * N + col] = f2bf(v);
                else          ((float*)Cv)[(size_t)row * N + col] = v;
            }
        }
    }
}

// ============ fused attention: logits + softmax + energies + PV ============
// One block per (bh, 64-row strip). Q resident in LDS. Two passes over j-tiles:
// pass1 = online row max/sum (no writes), pass2 = write w + energies + PV MFMA.

// stage a 64-row x 128B tile into LDS with source-side XOR swizzle (linear dest)
__device__ __forceinline__ void stage64(const unsigned short* gbase, size_t gstride,
                                        unsigned short* Xs, int wave, int lane)
{
    const int r8 = lane >> 3, g = lane & 7;
#pragma unroll
    for (int is = 0; is < 2; ++is) {
        const int row = wave * 16 + is * 8 + r8;
        gload_lds16(gbase + (size_t)row * gstride + ((g ^ (row & 7)) << 3),
                    Xs + (size_t)(wave * 16 + is * 8) * 64);
    }
}
// read a 16B fragment group g of row `row` (inverse of the stage swizzle)
__device__ __forceinline__ short8 frag64(const unsigned short* Xs, int row, int g) {
    return *(const short8*)&Xs[row * 64 + ((g ^ (row & 7)) << 3)];
}

__global__ __launch_bounds__(256)
void attn_fused_kernel(const unsigned short* __restrict__ qkvb,
                       const unsigned short* __restrict__ vT,
                       const float* __restrict__ dists,
                       float* __restrict__ wout,
                       unsigned short* __restrict__ attn,
                       float* __restrict__ out_e)
{
    __shared__ __align__(16) unsigned short Qs[64 * 64];
    __shared__ __align__(16) unsigned short Ks[64 * 64];
    __shared__ __align__(16) unsigned short Vs[64 * 64];
    __shared__ __align__(16) unsigned short Ws[64 * 64];
    __shared__ float mpart[4][64], spart[4][64];
    __shared__ float rowMx[64], rowInv[64];
    __shared__ float red[4];

    const int bh = blockIdx.x;
    const int yy = blockIdx.y;
    // work-balance interleave: {31..24},{16..23},{15..8},{0..7}
    const int it = (yy < 8) ? 31 - yy : (yy < 16) ? yy + 8 : (yy < 24) ? 31 - yy : yy - 24;
    const int b = bh >> 4, hh = bh & 15;
    const int i0 = it << 6;

    const int tid = threadIdx.x;
    const int wave = tid >> 6, lane = tid & 63;
    const int wm = (wave & 1) * 32;   // i sub-tile
    const int wn = (wave >> 1) * 32;  // j (or d) sub-tile
    const int frow = lane & 15;

    const unsigned short* Qg = qkvb + (size_t)(b * T_ + i0) * TD3_ + hh * DH_;
    const unsigned short* Kg = qkvb + (size_t)(b * T_) * TD3_ + D_ + hh * DH_;
    const unsigned short* Vg = vT + (size_t)(b * D_ + hh * DH_) * T_;
    const float* dbase = dists + (size_t)b * T_ * T_;
    float* wbh = wout + (size_t)bh * T_ * T_;

    stage64(Qg, TD3_, Qs, wave, lane);

    // ---------------- pass 1: per-row online max/sum ----------------
    float mloc[8], sloc[8];
#pragma unroll
    for (int s = 0; s < 8; ++s) { mloc[s] = -3.4e38f; sloc[s] = 0.f; }

    for (int jt = 0; jt <= it; ++jt) {
        __syncthreads();                       // Ks free (prev tile consumed)
        stage64(Kg + (size_t)(jt << 6) * TD3_, TD3_, Ks, wave, lane);
        __syncthreads();                       // Qs+Ks ready
        floatx4 acc[2][2];
#pragma unroll
        for (int i = 0; i < 2; ++i)
#pragma unroll
            for (int j = 0; j < 2; ++j) acc[i][j] = (floatx4){0.f, 0.f, 0.f, 0.f};
#pragma unroll
        for (int kk = 0; kk < 2; ++kk) {
            const int g = kk * 4 + (lane >> 4);
            short8 aq[2], bk[2];
#pragma unroll
            for (int mi = 0; mi < 2; ++mi) aq[mi] = frag64(Qs, wm + mi * 16 + frow, g);
#pragma unroll
            for (int ni = 0; ni < 2; ++ni) bk[ni] = frag64(Ks, wn + ni * 16 + frow, g);
#pragma unroll
            for (int mi = 0; mi < 2; ++mi)
#pragma unroll
                for (int ni = 0; ni < 2; ++ni)
                    acc[mi][ni] = __builtin_amdgcn_mfma_f32_16x16x32_bf16(
                        aq[mi], bk[ni], acc[mi][ni], 0, 0, 0);
        }
        const bool diag = (jt == it);
        const int j0 = jt << 6;
#pragma unroll
        for (int mi = 0; mi < 2; ++mi)
#pragma unroll
            for (int r = 0; r < 4; ++r) {
                const int gi = i0 + wm + mi * 16 + (lane >> 4) * 4 + r;
                const float* drow = dbase + (size_t)gi * T_;
                const int sl = mi * 4 + r;
#pragma unroll
                for (int ni = 0; ni < 2; ++ni) {
                    const int gj = j0 + wn + ni * 16 + (lane & 15);
                    const float x = acc[mi][ni][r] * 0.125f - drow[gj];
                    if (!diag || gj <= gi) {
                        const float m0 = mloc[sl];
                        const float mn = fmaxf(m0, x);
                        sloc[sl] = sloc[sl] * __expf(m0 - mn) + __expf(x - mn);
                        mloc[sl] = mn;
                    }
                }
            }
    }

    // combine 16 col-lanes via butterfly, then cross-wave via LDS
#pragma unroll
    for (int sl = 0; sl < 8; ++sl) {
        float m = mloc[sl], s = sloc[sl];
#pragma unroll
        for (int off = 1; off < 16; off <<= 1) {
            const float mo = __shfl_xor(m, off, 64);
            const float so = __shfl_xor(s, off, 64);
            const float mn = fmaxf(m, mo);
            s = s * __expf(m - mn) + so * __expf(mo - mn);
            m = mn;
        }
        mloc[sl] = m; sloc[sl] = s;
    }
    __syncthreads();
    if ((lane & 15) == 0) {
#pragma unroll
        for (int mi = 0; mi < 2; ++mi)
#pragma unroll
            for (int r = 0; r < 4; ++r) {
                const int row = wm + mi * 16 + (lane >> 4) * 4 + r;
                mpart[wave][row] = mloc[mi * 4 + r];
                spart[wave][row] = sloc[mi * 4 + r];
            }
    }
    __syncthreads();
    if (tid < 64) {
        const int wa = (tid >= 32) ? 1 : 0;
        const float m1 = mpart[wa][tid],     s1 = spart[wa][tid];
        const float m2 = mpart[wa + 2][tid], s2 = spart[wa + 2][tid];
        const float mn = fmaxf(m1, m2);
        const float ss = s1 * __expf(m1 - mn) + s2 * __expf(m2 - mn);
        rowMx[tid] = mn;
        rowInv[tid] = 1.0f / ss;
    }
    __syncthreads();

    float rM[8], rI[8];
#pragma unroll
    for (int mi = 0; mi < 2; ++mi)
#pragma unroll
        for (int r = 0; r < 4; ++r) {
            const int row = wm + mi * 16 + (lane >> 4) * 4 + r;
            rM[mi * 4 + r] = rowMx[row];
            rI[mi * 4 + r] = rowInv[row];
        }

    // ---------------- pass 2: write w, energies, PV ----------------
    floatx4 acco[2][2];
#pragma unroll
    for (int i = 0; i < 2; ++i)
#pragma unroll
        for (int j = 0; j < 2; ++j) acco[i][j] = (floatx4){0.f, 0.f, 0.f, 0.f};
    float de = 0.f, fe = 0.f;

    for (int jt = 0; jt <= it; ++jt) {
        __syncthreads();                       // Ks/Vs/Ws free
        stage64(Kg + (size_t)(jt << 6) * TD3_, TD3_, Ks, wave, lane);
        stage64(Vg + (jt << 6), T_, Vs, wave, lane);
        __syncthreads();                       // tiles ready
        floatx4 acc[2][2];
#pragma unroll
        for (int i = 0; i < 2; ++i)
#pragma unroll
            for (int j = 0; j < 2; ++j) acc[i][j] = (floatx4){0.f, 0.f, 0.f, 0.f};
#pragma unroll
        for (int kk = 0; kk < 2; ++kk) {
            const int g = kk * 4 + (lane >> 4);
            short8 aq[2], bk[2];
#pragma unroll
            for (int mi = 0; mi < 2; ++mi) aq[mi] = frag64(Qs, wm + mi * 16 + frow, g);
#pragma unroll
            for (int ni = 0; ni < 2; ++ni) bk[ni] = frag64(Ks, wn + ni * 16 + frow, g);
#pragma unroll
            for (int mi = 0; mi < 2; ++mi)
#pragma unroll
                for (int ni = 0; ni < 2; ++ni)
                    acc[mi][ni] = __builtin_amdgcn_mfma_f32_16x16x32_bf16(
                        aq[mi], bk[ni], acc[mi][ni], 0, 0, 0);
        }
        const bool diag = (jt == it);
        const int j0 = jt << 6;
#pragma unroll
        for (int mi = 0; mi < 2; ++mi)
#pragma unroll
            for (int r = 0; r < 4; ++r) {
                const int irow = wm + mi * 16 + (lane >> 4) * 4 + r;
                const int gi = i0 + irow;
                const float* drow = dbase + (size_t)gi * T_;
                float* wrow = wbh + (size_t)gi * T_;
                const int sl = mi * 4 + r;
#pragma unroll
                for (int ni = 0; ni < 2; ++ni) {
                    const int jcol = wn + ni * 16 + (lane & 15);
                    const int gj = j0 + jcol;
                    const float d = drow[gj];
                    const float s = acc[mi][ni][r] * 0.125f - d;
                    const float w = (diag && gj > gi) ? 0.f
                                  : __expf(s - rM[sl]) * rI[sl];
                    wrow[gj] = w;
                    de += w * d;
                    fe -= w * logf(w + 1e-9f);
                    Ws[irow * 64 + ((((jcol >> 3) ^ (irow & 7)) << 3) | (jcol & 7))] = f2bf(w);
                }
            }
        __syncthreads();                       // Ws ready
#pragma unroll
        for (int kk = 0; kk < 2; ++kk) {
            const int g = kk * 4 + (lane >> 4);
            short8 aw[2], bv[2];
#pragma unroll
            for (int mi = 0; mi < 2; ++mi) aw[mi] = frag64(Ws, wm + mi * 16 + frow, g);
#pragma unroll
            for (int ni = 0; ni < 2; ++ni) bv[ni] = frag64(Vs, wn + ni * 16 + frow, g);
#pragma unroll
            for (int mi = 0; mi < 2; ++mi)
#pragma unroll
                for (int ni = 0; ni < 2; ++ni)
                    acco[mi][ni] = __builtin_amdgcn_mfma_f32_16x16x32_bf16(
                        aw[mi], bv[ni], acco[mi][ni], 0, 0, 0);
        }
    }

    // zero-fill strict upper tiles (contiguous per row)
    {
        const int z0 = (it + 1) << 6;
        if (z0 < T_) {
            float* wrow = wbh + (size_t)(i0 + (tid >> 2)) * T_;
            const float4 z = {0.f, 0.f, 0.f, 0.f};
            for (int c = z0 + (tid & 3) * 4; c < T_; c += 16)
                *(float4*)(wrow + c) = z;
        }
    }

    // write attn tile: C rows = i, cols = d
#pragma unroll
    for (int ni = 0; ni < 2; ++ni) {
        const int d = wn + ni * 16 + (lane & 15);
#pragma unroll
        for (int mi = 0; mi < 2; ++mi)
#pragma unroll
            for (int r = 0; r < 4; ++r) {
                const int gi = i0 + wm + mi * 16 + (lane >> 4) * 4 + r;
                attn[((size_t)(b * T_ + gi)) * D_ + hh * DH_ + d] = f2bf(acco[mi][ni][r]);
            }
    }

    de = block_sum(de, red);
    fe = block_sum(fe, red);
    if (tid == 0) {
        atomicAdd(&out_e[0], de * (1.0f / BHT_));
        atomicAdd(&out_e[1], fe * (1.0f / BHT_));
    }
}

// ---------------- launch ----------------
extern "C" void kernel_launch(void* const* d_in, const int* in_sizes, int n_in,
                              void* d_out_v, int out_size, void* d_ws, size_t ws_size,
                              hipStream_t stream)
{
    const float* x    = (const float*)d_in[0];
    const float* td   = (const float*)d_in[1];
    const float* ln1g = (const float*)d_in[2];
    const float* ln1b = (const float*)d_in[3];
    const float* wqkv = (const float*)d_in[4];
    const float* wproj= (const float*)d_in[5];
    const float* ln2g = (const float*)d_in[6];
    const float* ln2b = (const float*)d_in[7];
    const float* w1   = (const float*)d_in[8];
    const float* b1   = (const float*)d_in[9];
    const float* w2   = (const float*)d_in[10];
    const float* b2   = (const float*)d_in[11];
    float* out = (float*)d_out_v;

    // output layout: x (4194304) | dist_e (1) | flop_e (1) | w (134217728) | token_dists (8388608)
    float* out_x  = out;
    float* out_e  = out + 4194304;
    float* out_w  = out + 4194306;
    float* out_td = out + 138412034;

    char* p = (char*)d_ws;
    unsigned short* qkvb = (unsigned short*)p; p += (size_t)NROWS_ * TD3_ * 2;       // bf16 qkv, 24MB
    float* x1    = (float*)p;              p += (size_t)NROWS_ * D_ * 4;             // 16MB
    unsigned short* hb    = (unsigned short*)p; p += (size_t)NROWS_ * D_ * 2;        // 8MB
    unsigned short* attnb = (unsigned short*)p; p += (size_t)NROWS_ * D_ * 2;        // 8MB
    unsigned short* h2b   = (unsigned short*)p; p += (size_t)NROWS_ * D_ * 2;        // 8MB
    unsigned short* ffn1b = (unsigned short*)p; p += (size_t)NROWS_ * 4 * D_ * 2;    // 32MB
    unsigned short* wqkvT = (unsigned short*)p; p += (size_t)TD3_ * D_ * 2;          // 6MB
    unsigned short* wprojT= (unsigned short*)p; p += (size_t)D_ * D_ * 2;            // 2MB
    unsigned short* w1T   = (unsigned short*)p; p += (size_t)4 * D_ * D_ * 2;        // 8MB
    unsigned short* w2T   = (unsigned short*)p; p += (size_t)4 * D_ * D_ * 2;        // 8MB
    unsigned short* vTb   = (unsigned short*)p; p += (size_t)B_ * D_ * T_ * 2;       // 8MB

    hipMemsetAsync(out_e, 0, 2 * sizeof(float), stream);

    // weight transposes (fp32 [K][N] -> bf16 [N][K])
    transpose_bf16_kernel<<<dim3(TD3_ / 32, D_ / 32), 256, 0, stream>>>(wqkv, wqkvT, D_, TD3_);
    transpose_bf16_kernel<<<dim3(D_ / 32, D_ / 32), 256, 0, stream>>>(wproj, wprojT, D_, D_);
    transpose_bf16_kernel<<<dim3(4 * D_ / 32, D_ / 32), 256, 0, stream>>>(w1, w1T, D_, 4 * D_);
    transpose_bf16_kernel<<<dim3(D_ / 32, 4 * D_ / 32), 256, 0, stream>>>(w2, w2T, 4 * D_, D_);

    ln_bf16_kernel<<<NROWS_, 256, 0, stream>>>(x, ln1g, ln1b, hb);

    // QKV GEMM -> bf16 output
    gemm_bt_kernel<1, 0, 0, 0><<<dim3(NROWS_ / 128, TD3_ / 128), 256, 0, stream>>>(
        hb, wqkvT, nullptr, nullptr, qkvb, NROWS_, TD3_, D_);

    // V^T extraction (bf16 [b][d][t])
    vT_kernel<<<dim3(T_ / 32, D_ / 32, B_), 256, 0, stream>>>(qkvb, vTb);

    // fused logits + softmax + energies + PV
    attn_fused_kernel<<<dim3(B_ * H_, T_ / 64), 256, 0, stream>>>(
        qkvb, vTb, td, out_w, attnb, out_e);

    gemm_bt_kernel<0, 0, 0, 1><<<dim3(NROWS_ / 128, D_ / 128), 256, 0, stream>>>(
        attnb, wprojT, nullptr, x, x1, NROWS_, D_, D_);

    ln_bf16_kernel<<<NROWS_, 256, 0, stream>>>(x1, ln2g, ln2b, h2b);

    gemm_bt_kernel<1, 1, 1, 0><<<dim3(NROWS_ / 128, 4 * D_ / 128), 256, 0, stream>>>(
        h2b, w1T, b1, nullptr, ffn1b, NROWS_, 4 * D_, D_);

    gemm_bt_kernel<0, 0, 1, 1><<<dim3(NROWS_ / 128, D_ / 128), 256, 0, stream>>>(
        ffn1b, w2T, b2, x1, out_x, NROWS_, D_, 4 * D_);

    hipMemcpyAsync(out_td, td, (size_t)B_ * T_ * T_ * sizeof(float),
                   hipMemcpyDeviceToDevice, stream);
}